// Round 1
// baseline (178.681 us; speedup 1.0000x reference)
//
#include <hip/hip_runtime.h>
#include <hip/hip_bf16.h>

typedef __bf16 bf16_t;
typedef __bf16 bf16x8 __attribute__((ext_vector_type(8)));
typedef float f32x4 __attribute__((ext_vector_type(4)));

// ---------------------------------------------------------------------------
// fp32 -> bf16 conversion, 8 elems/thread (vectorized loads/stores, G13)
// ---------------------------------------------------------------------------
__global__ __launch_bounds__(256)
void cvt_f32_bf16(const float* __restrict__ in, bf16_t* __restrict__ out, int n8) {
    int i = blockIdx.x * 256 + threadIdx.x;
    if (i >= n8) return;
    float4 a = ((const float4*)in)[i * 2];
    float4 b = ((const float4*)in)[i * 2 + 1];
    bf16x8 v;
    v[0] = (bf16_t)a.x; v[1] = (bf16_t)a.y; v[2] = (bf16_t)a.z; v[3] = (bf16_t)a.w;
    v[4] = (bf16_t)b.x; v[5] = (bf16_t)b.y; v[6] = (bf16_t)b.z; v[7] = (bf16_t)b.w;
    ((bf16x8*)out)[i] = v;
}

// ---------------------------------------------------------------------------
// gemm_bt: C[M,N] = A[M,K] * B[N,K]^T  (both row-major, K contiguous)
// m97 structure: 128x128 tile, BK=64, 4 waves (2x2 of 64x64), 16x16x32 MFMA,
// global_load_lds width=16, linear LDS, 2 barriers per K-step.
// EPI: 0 = fp32 out (batched via sA/sB/sC strides), no bias
//      1 = bf16 out + bias[col]        (fp32 bias)
//      2 = bf16 out + bias[col & 255]  (fp32 bias)
// All of M%128, N%128, K%64 are 0 for our shapes -> no bounds checks.
// ---------------------------------------------------------------------------
template <int EPI>
__global__ __launch_bounds__(256)
void gemm_bt(const bf16_t* __restrict__ A, const bf16_t* __restrict__ Bm,
             void* __restrict__ Cv, const float* __restrict__ bias,
             int M, int N, int K, long sA, long sB, long sC) {
    __shared__ bf16_t As[128 * 64];
    __shared__ bf16_t Bs[128 * 64];

    const int tid  = threadIdx.x;
    const int lane = tid & 63;
    const int wave = tid >> 6;
    const int mblk = blockIdx.x, nblk = blockIdx.y, bz = blockIdx.z;

    const bf16_t* Ab = A + (long)bz * sA + (long)mblk * 128 * K;
    const bf16_t* Bb = Bm + (long)bz * sB + (long)nblk * 128 * K;

    f32x4 acc[4][4] = {};

    const int wrow = (wave >> 1) * 64;  // wave's M offset within tile
    const int wcol = (wave & 1) * 64;   // wave's N offset within tile
    const int lrow = lane & 15;
    const int kgrp = lane >> 4;

    for (int k0 = 0; k0 < K; k0 += 64) {
        // stage A and B tiles: 128x64 bf16 = 16 KB each; 4 chunks of 16B/thread
#pragma unroll
        for (int it = 0; it < 4; ++it) {
            const int chunk = it * 256 + tid;       // 0..1023
            const int row = chunk >> 3, c8 = chunk & 7;
            __builtin_amdgcn_global_load_lds(
                (const __attribute__((address_space(1))) void*)(Ab + (long)row * K + k0 + c8 * 8),
                (__attribute__((address_space(3))) void*)(As + chunk * 8), 16, 0, 0);
            __builtin_amdgcn_global_load_lds(
                (const __attribute__((address_space(1))) void*)(Bb + (long)row * K + k0 + c8 * 8),
                (__attribute__((address_space(3))) void*)(Bs + chunk * 8), 16, 0, 0);
        }
        __syncthreads();  // drains vmcnt (compiler emits waitcnt before barrier)

#pragma unroll
        for (int kk = 0; kk < 64; kk += 32) {
            const int koff = kk + kgrp * 8;
            bf16x8 af[4], bf[4];
#pragma unroll
            for (int m = 0; m < 4; ++m)
                af[m] = *(const bf16x8*)(As + (wrow + m * 16 + lrow) * 64 + koff);
#pragma unroll
            for (int n = 0; n < 4; ++n)
                bf[n] = *(const bf16x8*)(Bs + (wcol + n * 16 + lrow) * 64 + koff);
#pragma unroll
            for (int m = 0; m < 4; ++m)
#pragma unroll
                for (int n = 0; n < 4; ++n)
                    acc[m][n] = __builtin_amdgcn_mfma_f32_16x16x32_bf16(af[m], bf[n], acc[m][n], 0, 0, 0);
        }
        __syncthreads();
    }

    // C/D layout (m89/m91 verified): col = lane&15, row = (lane>>4)*4 + j
    const long rbase = (long)mblk * 128 + wrow + kgrp * 4;
    const long cb0   = (long)nblk * 128 + wcol + lrow;
    if constexpr (EPI == 0) {
        float* C = (float*)Cv + (long)bz * sC;
#pragma unroll
        for (int m = 0; m < 4; ++m)
#pragma unroll
            for (int n = 0; n < 4; ++n) {
                const long col = cb0 + n * 16;
#pragma unroll
                for (int j = 0; j < 4; ++j)
                    C[(rbase + m * 16 + j) * N + col] = acc[m][n][j];
            }
    } else {
        bf16_t* C = (bf16_t*)Cv;
#pragma unroll
        for (int n = 0; n < 4; ++n) {
            const long col = cb0 + n * 16;
            const float bv = (EPI == 1) ? bias[col] : bias[col & 255];
#pragma unroll
            for (int m = 0; m < 4; ++m)
#pragma unroll
                for (int j = 0; j < 4; ++j)
                    C[(rbase + m * 16 + j) * N + col] = (bf16_t)(acc[m][n][j] + bv);
        }
    }
}

// ---------------------------------------------------------------------------
// B=8, S=1024, IN=768, E=256, L=12
//   t  = input[8192,768] @ fc_w[256,768]^T + fc_b          -> bf16 [8192,256]
//   bl = t[8192,256] @ bi_w[3072,256]^T + bias[col&255]    -> bf16 [8192,3072]
//        (flat [B,S,L,E] layout == [8192,3072] row-major)
//   out_b = bl_b[12288,256] @ t_b[1024,256]^T              -> f32, batched x8
// ---------------------------------------------------------------------------
extern "C" void kernel_launch(void* const* d_in, const int* in_sizes, int n_in,
                              void* d_out, int out_size, void* d_ws, size_t ws_size,
                              hipStream_t stream) {
    const float* input = (const float*)d_in[0];
    const float* fc_w  = (const float*)d_in[1];
    const float* fc_b  = (const float*)d_in[2];
    const float* bi_w  = (const float*)d_in[3];
    const float* bias  = (const float*)d_in[4];

    char* ws = (char*)d_ws;
    bf16_t* inA = (bf16_t*)(ws);             // 8192*768*2  = 12,582,912
    bf16_t* wfc = (bf16_t*)(ws + 12582912);  // 256*768*2   =    393,216
    bf16_t* wbi = (bf16_t*)(ws + 12976128);  // 3072*256*2  =  1,572,864
    bf16_t* t   = (bf16_t*)(ws + 14548992);  // 8192*256*2  =  4,194,304
    bf16_t* bl  = (bf16_t*)(ws + 18743296);  // 8192*3072*2 = 50,331,648
                                             // total ~69 MB

    {
        int n8 = (8192 * 768) / 8;
        cvt_f32_bf16<<<dim3((n8 + 255) / 256), dim3(256), 0, stream>>>(input, inA, n8);
    }
    {
        int n8 = (256 * 768) / 8;
        cvt_f32_bf16<<<dim3((n8 + 255) / 256), dim3(256), 0, stream>>>(fc_w, wfc, n8);
    }
    {
        int n8 = (3072 * 256) / 8;
        cvt_f32_bf16<<<dim3((n8 + 255) / 256), dim3(256), 0, stream>>>(bi_w, wbi, n8);
    }

    // GEMM1: t = inA @ wfc^T + fc_b
    gemm_bt<1><<<dim3(64, 2, 1), dim3(256), 0, stream>>>(
        inA, wfc, (void*)t, fc_b, 8192, 256, 768, 0L, 0L, 0L);

    // GEMM2: bl = t @ wbi^T + bias[col&255]
    gemm_bt<2><<<dim3(64, 24, 1), dim3(256), 0, stream>>>(
        t, wbi, (void*)bl, bias, 8192, 3072, 256, 0L, 0L, 0L);

    // GEMM3 (batched over 8): out_b = bl_b @ t_b^T
    gemm_bt<0><<<dim3(96, 8, 8), dim3(256), 0, stream>>>(
        bl, t, d_out, nullptr, 12288, 1024, 256,
        (long)12288 * 256, (long)1024 * 256, (long)12288 * 1024);
}